// Round 3
// baseline (5007.990 us; speedup 1.0000x reference)
//
#include <hip/hip_runtime.h>
#include <math.h>

#define HDIM 128
#define NIN_ 32
#define RANKS 3

typedef unsigned int u32;
typedef unsigned short u16;

// ---- bf16 helpers (storage bf16, compute fp32) ----------------------------
__device__ __forceinline__ float bf2f(u16 b) { return __uint_as_float(((u32)b) << 16); }
__device__ __forceinline__ u16 f2bf(float f) {
    u32 u = __float_as_uint(f);
    u32 r = u + 0x7fffu + ((u >> 16) & 1u);  // round-to-nearest-even
    return (u16)(r >> 16);
}
__device__ __forceinline__ float sigmoidf_(float x) { return 1.0f / (1.0f + expf(-x)); }
__device__ __forceinline__ float siluf_(float x) { return x / (1.0f + expf(-x)); }

// ---------------------------------------------------------------------------
// Zero-fill (replaces hipMemsetAsync: memsets did not replay inside the graph)
// ---------------------------------------------------------------------------
__global__ void zero_kernel(u32* __restrict__ p, long long nw) {
    long long i = (long long)blockIdx.x * blockDim.x + threadIdx.x;
    long long stride = (long long)gridDim.x * blockDim.x;
    for (; i < nw; i += stride) p[i] = 0u;
}

// ---------------------------------------------------------------------------
// h(bf16) = x(f32) @ w_emb + b_emb   (x: [n,32], w: [32,128])
// ---------------------------------------------------------------------------
template <int TR>
__global__ void embed_bf_kernel(const float* __restrict__ x, const float* __restrict__ w,
                                const float* __restrict__ b, u16* __restrict__ h, int n) {
    __shared__ float xs[TR][NIN_];
    const int row0 = blockIdx.x * TR;
    const int c = threadIdx.x;  // 0..127

    for (int i = c; i < TR * NIN_; i += HDIM) {
        int r = i >> 5, k = i & 31;
        int gr = row0 + r;
        xs[r][k] = (gr < n) ? x[(long long)gr * NIN_ + k] : 0.0f;
    }
    __syncthreads();

    float acc[TR];
    const float bias = b[c];
#pragma unroll
    for (int r = 0; r < TR; ++r) acc[r] = bias;
    for (int k = 0; k < NIN_; ++k) {
        float wv = w[k * HDIM + c];
#pragma unroll
        for (int r = 0; r < TR; ++r) acc[r] = fmaf(xs[r][k], wv, acc[r]);
    }
#pragma unroll
    for (int r = 0; r < TR; ++r) {
        int gr = row0 + r;
        if (gr < n) h[(long long)gr * HDIM + c] = f2bf(acc[r]);
    }
}

// ---------------------------------------------------------------------------
// dst[cols[e]] += src[rows[e]]  — bf16x2 words, CAS accumulate.
// ---------------------------------------------------------------------------
__global__ void scatter_bf_kernel(const u32* __restrict__ src, const int* __restrict__ rows,
                                  const int* __restrict__ cols, u32* __restrict__ dst, int nnz) {
    long long tid = (long long)blockIdx.x * blockDim.x + threadIdx.x;
    if (tid >= (long long)nnz * 64) return;
    int e = (int)(tid >> 6);
    int wd = (int)(tid & 63);
    int r = rows[e];
    int d = cols[e];
    u32 s = src[(long long)r * 64 + wd];
    float xlo = bf2f((u16)(s & 0xffffu));
    float xhi = bf2f((u16)(s >> 16));
    u32* a = dst + (long long)d * 64 + wd;
    u32 old = *a;
    while (true) {
        float lo = bf2f((u16)(old & 0xffffu)) + xlo;
        float hi = bf2f((u16)(old >> 16)) + xhi;
        u32 nv = ((u32)f2bf(hi) << 16) | (u32)f2bf(lo);
        u32 got = atomicCAS(a, old, nv);
        if (got == old) break;
        old = got;
    }
}

// ---------------------------------------------------------------------------
// In-place elementwise sigmoid on bf16 buffer (u32 = 2 elems per thread).
// ---------------------------------------------------------------------------
__global__ void sigmoid_bf_kernel(u32* __restrict__ h, long long nw) {
    long long i = (long long)blockIdx.x * blockDim.x + threadIdx.x;
    long long stride = (long long)gridDim.x * blockDim.x;
    for (; i < nw; i += stride) {
        u32 v = h[i];
        float lo = sigmoidf_(bf2f((u16)(v & 0xffffu)));
        float hi = sigmoidf_(bf2f((u16)(v >> 16)));
        h[i] = ((u32)f2bf(hi) << 16) | (u32)f2bf(lo);
    }
}

// ---------------------------------------------------------------------------
// In-place hm[r,:] = sigmoid(hm[r,:] @ w)   (hm bf16 [n,128], w f32 128x128)
// ---------------------------------------------------------------------------
template <int TR>
__global__ void conv_bf_kernel(u16* __restrict__ hm, const float* __restrict__ w, int n) {
    __shared__ float ms[TR][HDIM];
    const int row0 = blockIdx.x * TR;
    const int c = threadIdx.x;

#pragma unroll
    for (int r = 0; r < TR; ++r) {
        int gr = row0 + r;
        ms[r][c] = (gr < n) ? bf2f(hm[(long long)gr * HDIM + c]) : 0.0f;
    }
    __syncthreads();

    float acc[TR];
#pragma unroll
    for (int r = 0; r < TR; ++r) acc[r] = 0.0f;
    for (int k = 0; k < HDIM; ++k) {
        float wv = w[k * HDIM + c];
#pragma unroll
        for (int r = 0; r < TR; ++r) acc[r] = fmaf(ms[r][k], wv, acc[r]);
    }
#pragma unroll
    for (int r = 0; r < TR; ++r) {
        int gr = row0 + r;
        if (gr < n) hm[(long long)gr * HDIM + c] = f2bf(sigmoidf_(acc[r]));
    }
}

// ---------------------------------------------------------------------------
// Fused pre_pool + global_add_pool (h bf16; compute & pool fp32)
// ---------------------------------------------------------------------------
template <int TR>
__global__ void prepool_bf_kernel(const u16* __restrict__ h, const float* __restrict__ w1,
                                  const float* __restrict__ b1, const float* __restrict__ w2,
                                  const float* __restrict__ b2, const int* __restrict__ batch,
                                  float* __restrict__ p, int n, int colOff) {
    __shared__ float hs[TR][HDIM];
    __shared__ float zs[TR][HDIM];
    const int row0 = blockIdx.x * TR;
    const int c = threadIdx.x;

#pragma unroll
    for (int r = 0; r < TR; ++r) {
        int gr = row0 + r;
        hs[r][c] = (gr < n) ? bf2f(h[(long long)gr * HDIM + c]) : 0.0f;
    }
    __syncthreads();

    float acc[TR];
    const float bias1 = b1[c];
#pragma unroll
    for (int r = 0; r < TR; ++r) acc[r] = bias1;
    for (int k = 0; k < HDIM; ++k) {
        float wv = w1[k * HDIM + c];
#pragma unroll
        for (int r = 0; r < TR; ++r) acc[r] = fmaf(hs[r][k], wv, acc[r]);
    }
#pragma unroll
    for (int r = 0; r < TR; ++r) zs[r][c] = siluf_(acc[r]);
    __syncthreads();

    const float bias2 = b2[c];
#pragma unroll
    for (int r = 0; r < TR; ++r) acc[r] = bias2;
    for (int k = 0; k < HDIM; ++k) {
        float wv = w2[k * HDIM + c];
#pragma unroll
        for (int r = 0; r < TR; ++r) acc[r] = fmaf(zs[r][k], wv, acc[r]);
    }

    float cur = 0.0f;
    int curb = -1;
#pragma unroll
    for (int r = 0; r < TR; ++r) {
        int gr = row0 + r;
        if (gr < n) {
            int bg = batch[gr];
            if (bg != curb) {
                if (curb >= 0) atomicAdd(&p[curb * (RANKS * HDIM) + colOff + c], cur);
                curb = bg;
                cur = 0.0f;
            }
            cur += acc[r];
        }
    }
    if (curb >= 0) atomicAdd(&p[curb * (RANKS * HDIM) + colOff + c], cur);
}

// ---------------------------------------------------------------------------
// Final head: out[g] = silu(p[g] @ post_w1 + post_b1) @ post_w2 + post_b2
// ---------------------------------------------------------------------------
__global__ void final_kernel(const float* __restrict__ p, const float* __restrict__ w1,
                             const float* __restrict__ b1, const float* __restrict__ w2,
                             const float* __restrict__ b2, float* __restrict__ out) {
    const int g = blockIdx.x;
    const int c = threadIdx.x;  // 0..127
    const float* pg = p + g * (RANKS * HDIM);
    float acc = b1[c];
    for (int k = 0; k < RANKS * HDIM; ++k) acc = fmaf(pg[k], w1[k * HDIM + c], acc);
    float z = siluf_(acc);
    float v = z * w2[c];
#pragma unroll
    for (int off = 32; off > 0; off >>= 1) v += __shfl_down(v, off, 64);
    __shared__ float red[2];
    if ((c & 63) == 0) red[c >> 6] = v;
    __syncthreads();
    if (c == 0) out[g] = red[0] + red[1] + b2[0];
}

// ---------------------------------------------------------------------------
extern "C" void kernel_launch(void* const* d_in, const int* in_sizes, int n_in,
                              void* d_out, int out_size, void* d_ws, size_t ws_size,
                              hipStream_t stream) {
    const float* x0 = (const float*)d_in[0];
    const float* x1 = (const float*)d_in[1];
    const int* b1_rows = (const int*)d_in[3];
    const int* b1_cols = (const int*)d_in[4];
    const int* b2_rows = (const int*)d_in[5];
    const int* b2_cols = (const int*)d_in[6];
    const int* batch0 = (const int*)d_in[7];
    const int* batch1 = (const int*)d_in[8];
    const int* batch2 = (const int*)d_in[9];
    const float* w_emb = (const float*)d_in[10];
    const float* b_emb = (const float*)d_in[11];
    const float* conv_w = (const float*)d_in[12];
    const float* pre_w1 = (const float*)d_in[13];
    const float* pre_b1 = (const float*)d_in[14];
    const float* pre_w2 = (const float*)d_in[15];
    const float* pre_b2 = (const float*)d_in[16];
    const float* post_w1 = (const float*)d_in[17];
    const float* post_b1 = (const float*)d_in[18];
    const float* post_w2 = (const float*)d_in[19];
    const float* post_b2 = (const float*)d_in[20];

    const int N0 = in_sizes[0] / NIN_;
    const int N1 = in_sizes[1] / NIN_;
    const int N2 = in_sizes[2] / NIN_;
    const int NNZ1 = in_sizes[3];
    const int NNZ2 = in_sizes[5];
    const int L = in_sizes[12] / (2 * HDIM * HDIM);
    const int Gn = out_size;  // 256 graphs

    // workspace (bf16 state): A=h0 | B=h1 | C=h2 | p(fp32)  ~= 308 MB total
    u16* A = (u16*)d_ws;
    u16* B = A + (size_t)N0 * HDIM;
    u16* C = B + (size_t)N1 * HDIM;
    float* p = (float*)(C + (size_t)N2 * HDIM);

    constexpr int TR = 16;
    const int blk = HDIM;  // 128 threads
    const int ZB = 2048;   // zero-fill grid

    // 1) embedding for rank 0 (rank-2 embedding is dead; rank-1 only if L==1)
    embed_bf_kernel<TR><<<(N0 + TR - 1) / TR, blk, 0, stream>>>(x0, w_emb, b_emb, A, N0);

    // 2) layers (dead-code pruned: m2/h2 only computed in the last layer)
    for (int l = 0; l < L; ++l) {
        const bool last = (l == L - 1);
        const float* w_r1 = conv_w + (size_t)(l * 2 + 0) * HDIM * HDIM;
        const float* w_r2 = conv_w + (size_t)(l * 2 + 1) * HDIM * HDIM;

        if (last) {
            if (L == 1)
                embed_bf_kernel<TR><<<(N1 + TR - 1) / TR, blk, 0, stream>>>(x1, w_emb, b_emb, B, N1);
            // m2 = scatter(h1) -> C
            zero_kernel<<<ZB, 256, 0, stream>>>((u32*)C, (long long)N2 * (HDIM / 2));
            long long tot2 = (long long)NNZ2 * 64;
            scatter_bf_kernel<<<(int)((tot2 + 255) / 256), 256, 0, stream>>>(
                (const u32*)B, b2_rows, b2_cols, (u32*)C, NNZ2);
        }
        // m1 = scatter(h0) -> B
        zero_kernel<<<ZB, 256, 0, stream>>>((u32*)B, (long long)N1 * (HDIM / 2));
        long long tot1 = (long long)NNZ1 * 64;
        scatter_bf_kernel<<<(int)((tot1 + 255) / 256), 256, 0, stream>>>(
            (const u32*)A, b1_rows, b1_cols, (u32*)B, NNZ1);

        // h1 = sigmoid(m1 @ w_r1); h2 = sigmoid(m2 @ w_r2); h0 = sigmoid(h0)
        conv_bf_kernel<TR><<<(N1 + TR - 1) / TR, blk, 0, stream>>>(B, w_r1, N1);
        if (last)
            conv_bf_kernel<TR><<<(N2 + TR - 1) / TR, blk, 0, stream>>>(C, w_r2, N2);
        sigmoid_bf_kernel<<<2048, 256, 0, stream>>>((u32*)A, (long long)N0 * (HDIM / 2));
    }

    // 3) fused pre_pool + pooling
    zero_kernel<<<64, 256, 0, stream>>>((u32*)p, (long long)Gn * RANKS * HDIM);
    prepool_bf_kernel<TR><<<(N0 + TR - 1) / TR, blk, 0, stream>>>(
        A, pre_w1 + 0 * HDIM * HDIM, pre_b1 + 0 * HDIM, pre_w2 + 0 * HDIM * HDIM,
        pre_b2 + 0 * HDIM, batch0, p, N0, 0 * HDIM);
    prepool_bf_kernel<TR><<<(N1 + TR - 1) / TR, blk, 0, stream>>>(
        B, pre_w1 + 1 * HDIM * HDIM, pre_b1 + 1 * HDIM, pre_w2 + 1 * HDIM * HDIM,
        pre_b2 + 1 * HDIM, batch1, p, N1, 1 * HDIM);
    prepool_bf_kernel<TR><<<(N2 + TR - 1) / TR, blk, 0, stream>>>(
        C, pre_w1 + 2 * HDIM * HDIM, pre_b1 + 2 * HDIM, pre_w2 + 2 * HDIM * HDIM,
        pre_b2 + 2 * HDIM, batch2, p, N2, 2 * HDIM);

    // 4) head
    final_kernel<<<Gn, blk, 0, stream>>>(p, post_w1, post_b1, post_w2, post_b2,
                                         (float*)d_out);
}

// Round 4
// 2866.300 us; speedup vs baseline: 1.7472x; 1.7472x over previous
//
#include <hip/hip_runtime.h>
#include <math.h>

#define HDIM 128
#define NIN_ 32
#define RANKS 3

typedef unsigned int u32;
typedef unsigned short u16;
typedef __attribute__((ext_vector_type(8))) short short8;
typedef __attribute__((ext_vector_type(8))) __bf16 bf16x8;
typedef __attribute__((ext_vector_type(4))) float f32x4;

__device__ __forceinline__ float bf2f(u16 b) { return __uint_as_float(((u32)b) << 16); }
__device__ __forceinline__ u16 f2bf(float f) {
    u32 u = __float_as_uint(f);
    u32 r = u + 0x7fffu + ((u >> 16) & 1u);
    return (u16)(r >> 16);
}
__device__ __forceinline__ float sigmoidf_(float x) { return 1.0f / (1.0f + expf(-x)); }
__device__ __forceinline__ float siluf_(float x) { return x / (1.0f + expf(-x)); }

// ---------------------------------------------------------------------------
__global__ void zero_kernel(u32* __restrict__ p, long long nw) {
    long long i = (long long)blockIdx.x * blockDim.x + threadIdx.x;
    long long stride = (long long)gridDim.x * blockDim.x;
    for (; i < nw; i += stride) p[i] = 0u;
}

// ---------------------------------------------------------------------------
// h(bf16) = x(f32) @ w_emb + b_emb
// ---------------------------------------------------------------------------
template <int TR>
__global__ void embed_bf_kernel(const float* __restrict__ x, const float* __restrict__ w,
                                const float* __restrict__ b, u16* __restrict__ h, int n) {
    __shared__ float xs[TR][NIN_];
    const int row0 = blockIdx.x * TR;
    const int c = threadIdx.x;

    for (int i = c; i < TR * NIN_; i += HDIM) {
        int r = i >> 5, k = i & 31;
        int gr = row0 + r;
        xs[r][k] = (gr < n) ? x[(long long)gr * NIN_ + k] : 0.0f;
    }
    __syncthreads();

    float acc[TR];
    const float bias = b[c];
#pragma unroll
    for (int r = 0; r < TR; ++r) acc[r] = bias;
    for (int k = 0; k < NIN_; ++k) {
        float wv = w[k * HDIM + c];
#pragma unroll
        for (int r = 0; r < TR; ++r) acc[r] = fmaf(xs[r][k], wv, acc[r]);
    }
#pragma unroll
    for (int r = 0; r < TR; ++r) {
        int gr = row0 + r;
        if (gr < n) h[(long long)gr * HDIM + c] = f2bf(acc[r]);
    }
}

// ---------------------------------------------------------------------------
// dst[cols[e]] += src[rows[e]] — bf16x2 CAS accumulate (64 lanes per edge).
// ---------------------------------------------------------------------------
__global__ void scatter_bf_kernel(const u32* __restrict__ src, const int* __restrict__ rows,
                                  const int* __restrict__ cols, u32* __restrict__ dst, int nnz) {
    long long tid = (long long)blockIdx.x * blockDim.x + threadIdx.x;
    if (tid >= (long long)nnz * 64) return;
    int e = (int)(tid >> 6);
    int wd = (int)(tid & 63);
    int r = rows[e];
    int d = cols[e];
    u32 s = src[(long long)r * 64 + wd];
    float xlo = bf2f((u16)(s & 0xffffu));
    float xhi = bf2f((u16)(s >> 16));
    u32* a = dst + (long long)d * 64 + wd;
    u32 old = *a;
    while (true) {
        float lo = bf2f((u16)(old & 0xffffu)) + xlo;
        float hi = bf2f((u16)(old >> 16)) + xhi;
        u32 nv = ((u32)f2bf(hi) << 16) | (u32)f2bf(lo);
        u32 got = atomicCAS(a, old, nv);
        if (got == old) break;
        old = got;
    }
}

// ---------------------------------------------------------------------------
__global__ void sigmoid_bf_kernel(u32* __restrict__ h, long long nw) {
    long long i = (long long)blockIdx.x * blockDim.x + threadIdx.x;
    long long stride = (long long)gridDim.x * blockDim.x;
    for (; i < nw; i += stride) {
        u32 v = h[i];
        float lo = sigmoidf_(bf2f((u16)(v & 0xffffu)));
        float hi = sigmoidf_(bf2f((u16)(v >> 16)));
        h[i] = ((u32)f2bf(hi) << 16) | (u32)f2bf(lo);
    }
}

// ---------------------------------------------------------------------------
// Weight pre-transform: wt[mat][col*128 + (k ^ ((col&7)<<3))] = bf16(W[mat][k][col])
// Transposed (B^T form for MFMA B-frags) + XOR-swizzled for conflict-free ds_read_b128.
// mats: [0..2L) conv_w, [2L..2L+3) pre_w1, [2L+3..2L+6) pre_w2
// ---------------------------------------------------------------------------
__global__ void wprep_kernel(const float* __restrict__ conv_w, const float* __restrict__ pre_w1,
                             const float* __restrict__ pre_w2, u16* __restrict__ wt, int Lnum) {
    int tid = blockIdx.x * 256 + threadIdx.x;
    int nm = 2 * Lnum + 6;
    if (tid >= nm * 128 * 128) return;
    int m = tid >> 14;
    int r = tid & 16383;
    int k = r >> 7;
    int col = r & 127;
    const float* src;
    if (m < 2 * Lnum) src = conv_w + (size_t)m * 16384;
    else if (m < 2 * Lnum + 3) src = pre_w1 + (size_t)(m - 2 * Lnum) * 16384;
    else src = pre_w2 + (size_t)(m - 2 * Lnum - 3) * 16384;
    float v = src[k * 128 + col];
    wt[(size_t)m * 16384 + col * 128 + (k ^ ((col & 7) << 3))] = f2bf(v);
}

// ---------------------------------------------------------------------------
// MFMA conv: hm[r,:] = sigmoid(hm[r,:] @ W) in place.
// 512 thr = 8 waves, 128 rows/block (16 rows/wave). W pre-swizzled bf16 in LDS.
// A-frags direct from global (each row read by exactly one wave).
// ---------------------------------------------------------------------------
__global__ __launch_bounds__(512) void conv_mfma_kernel(u16* __restrict__ hm,
                                                        const u16* __restrict__ wt, int n) {
    __shared__ u16 wls[16384];        // 32 KB weights (pre-swizzled)
    __shared__ u16 cs[8][16][128];    // 32 KB epilogue staging (swizzled)
    const int tid = threadIdx.x;
    const int wave = tid >> 6, lane = tid & 63;
    const int row0 = blockIdx.x * 128;
    const int col = lane & 15, kg = lane >> 4;

    {   // stage weights: linear copy, conflict-free
        const uint4* g = (const uint4*)wt;
        uint4* l = (uint4*)wls;
        for (int i = tid; i < 2048; i += 512) l[i] = g[i];
    }
    __syncthreads();

    const int wrow0 = row0 + wave * 16;
    const int arow = wrow0 + col;
    const int arowc = arow < n ? arow : (n - 1);

    bf16x8 afrag[4];
    {
        const bf16x8* ap = (const bf16x8*)(hm + (size_t)arowc * HDIM + kg * 8);
#pragma unroll
        for (int k0 = 0; k0 < 4; ++k0) afrag[k0] = ap[k0 * 4];  // stride 32 elems
    }

    f32x4 acc[8];
#pragma unroll
    for (int ct = 0; ct < 8; ++ct) acc[ct] = (f32x4){0.f, 0.f, 0.f, 0.f};

#pragma unroll
    for (int ct = 0; ct < 8; ++ct) {
        int bcol = ct * 16 + col;
        const u16* bb = wls + bcol * 128;
        int swz = (bcol & 7) << 3;
#pragma unroll
        for (int k0 = 0; k0 < 4; ++k0) {
            bf16x8 bfrag = *(const bf16x8*)(bb + ((k0 * 32 + kg * 8) ^ swz));
            acc[ct] = __builtin_amdgcn_mfma_f32_16x16x32_bf16(afrag[k0], bfrag, acc[ct], 0, 0, 0);
        }
    }

    // epilogue: sigmoid -> bf16 -> swizzled LDS -> coalesced row stores
#pragma unroll
    for (int ct = 0; ct < 8; ++ct) {
#pragma unroll
        for (int r = 0; r < 4; ++r) {
            int crow = kg * 4 + r;
            cs[wave][crow][(ct * 16 + col) ^ ((crow & 7) << 3)] = f2bf(sigmoidf_(acc[ct][r]));
        }
    }
    // same-wave LDS write->read (lgkmcnt handled by compiler)
#pragma unroll
    for (int it = 0; it < 4; ++it) {
        int cid = it * 64 + lane;
        int r = cid >> 4, c = cid & 15;
        int grow = wrow0 + r;
        if (grow < n) {
            short8 v = *(const short8*)(&cs[wave][r][(c * 8) ^ ((r & 7) << 3)]);
            *(short8*)(hm + (size_t)grow * HDIM + c * 8) = v;
        }
    }
}

// ---------------------------------------------------------------------------
// MFMA prepool: y = silu(h@W1+b1)@W2+b2, segment-pooled into p by batch.
// 512 thr / 8 waves / 128 rows. W1 then W2 restaged in the same 32KB LDS.
// ---------------------------------------------------------------------------
__global__ __launch_bounds__(512) void prepool_mfma_kernel(
    const u16* __restrict__ h, const u16* __restrict__ w1t, const u16* __restrict__ w2t,
    const float* __restrict__ b1, const float* __restrict__ b2, const int* __restrict__ batch,
    float* __restrict__ p, int n, int colOff, int presig) {
    __shared__ u16 wls[16384];        // 32 KB weight buffer (restaged W1 -> W2)
    __shared__ u16 zs[8][16][128];    // 32 KB z staging (A-layout, swizzled)
    const int tid = threadIdx.x;
    const int wave = tid >> 6, lane = tid & 63;
    const int row0 = blockIdx.x * 128;
    const int col = lane & 15, kg = lane >> 4;
    const int wrow0 = row0 + wave * 16;

    {   // stage W1
        const uint4* g = (const uint4*)w1t;
        uint4* l = (uint4*)wls;
        for (int i = tid; i < 2048; i += 512) l[i] = g[i];
    }
    __syncthreads();

    const int arow = wrow0 + col;
    const int arowc = arow < n ? arow : (n - 1);
    bf16x8 afrag[4];
    {
        const bf16x8* ap = (const bf16x8*)(h + (size_t)arowc * HDIM + kg * 8);
#pragma unroll
        for (int k0 = 0; k0 < 4; ++k0) afrag[k0] = ap[k0 * 4];
    }
    if (presig) {   // fused h0 = sigmoid(h0) of the last layer
#pragma unroll
        for (int k0 = 0; k0 < 4; ++k0) {
            short8 s = __builtin_bit_cast(short8, afrag[k0]);
#pragma unroll
            for (int j = 0; j < 8; ++j) s[j] = (short)f2bf(sigmoidf_(bf2f((u16)s[j])));
            afrag[k0] = __builtin_bit_cast(bf16x8, s);
        }
    }

    f32x4 acc[8];
#pragma unroll
    for (int ct = 0; ct < 8; ++ct) acc[ct] = (f32x4){0.f, 0.f, 0.f, 0.f};
#pragma unroll
    for (int ct = 0; ct < 8; ++ct) {
        int bcol = ct * 16 + col;
        const u16* bb = wls + bcol * 128;
        int swz = (bcol & 7) << 3;
#pragma unroll
        for (int k0 = 0; k0 < 4; ++k0) {
            bf16x8 bfrag = *(const bf16x8*)(bb + ((k0 * 32 + kg * 8) ^ swz));
            acc[ct] = __builtin_amdgcn_mfma_f32_16x16x32_bf16(afrag[k0], bfrag, acc[ct], 0, 0, 0);
        }
    }
    // z = silu(acc + b1) -> swizzled zs
#pragma unroll
    for (int ct = 0; ct < 8; ++ct) {
        float b1v = b1[ct * 16 + col];
#pragma unroll
        for (int r = 0; r < 4; ++r) {
            int crow = kg * 4 + r;
            zs[wave][crow][(ct * 16 + col) ^ ((crow & 7) << 3)] = f2bf(siluf_(acc[ct][r] + b1v));
        }
    }
    __syncthreads();
    {   // restage W2
        const uint4* g = (const uint4*)w2t;
        uint4* l = (uint4*)wls;
        for (int i = tid; i < 2048; i += 512) l[i] = g[i];
    }
    __syncthreads();

    // gemm2: A from zs
    bf16x8 zfrag[4];
    {
        int zrow = lane & 15;
        int zswz = (zrow & 7) << 3;
#pragma unroll
        for (int k0 = 0; k0 < 4; ++k0)
            zfrag[k0] = *(const bf16x8*)(&zs[wave][zrow][(k0 * 32 + kg * 8) ^ zswz]);
    }
#pragma unroll
    for (int ct = 0; ct < 8; ++ct) acc[ct] = (f32x4){0.f, 0.f, 0.f, 0.f};
#pragma unroll
    for (int ct = 0; ct < 8; ++ct) {
        int bcol = ct * 16 + col;
        const u16* bb = wls + bcol * 128;
        int swz = (bcol & 7) << 3;
#pragma unroll
        for (int k0 = 0; k0 < 4; ++k0) {
            bf16x8 bfrag = *(const bf16x8*)(bb + ((k0 * 32 + kg * 8) ^ swz));
            acc[ct] = __builtin_amdgcn_mfma_f32_16x16x32_bf16(zfrag[k0], bfrag, acc[ct], 0, 0, 0);
        }
    }

    // pooling (batch sorted; segments are huge -> wave-uniform fast path)
    if (wrow0 < n) {
        int rend = wrow0 + 15 < n ? wrow0 + 15 : (n - 1);
        int bstart = batch[wrow0];
        int bend = batch[rend];
        if (bstart == bend) {
#pragma unroll
            for (int ct = 0; ct < 8; ++ct) {
                float b2v = b2[ct * 16 + col];
                float s = 0.f;
#pragma unroll
                for (int r = 0; r < 4; ++r) {
                    int row = wrow0 + kg * 4 + r;
                    if (row < n) s += acc[ct][r] + b2v;
                }
                s += __shfl_xor(s, 16, 64);
                s += __shfl_xor(s, 32, 64);
                if (kg == 0) atomicAdd(&p[bstart * (RANKS * HDIM) + colOff + ct * 16 + col], s);
            }
        } else {
            int bgs[4];
#pragma unroll
            for (int r = 0; r < 4; ++r) {
                int row = wrow0 + kg * 4 + r;
                bgs[r] = (row < n) ? batch[row] : -1;
            }
#pragma unroll
            for (int ct = 0; ct < 8; ++ct) {
                float b2v = b2[ct * 16 + col];
                int curb = -1;
                float cur = 0.f;
#pragma unroll
                for (int r = 0; r < 4; ++r) {
                    if (bgs[r] >= 0) {
                        if (bgs[r] != curb) {
                            if (curb >= 0)
                                atomicAdd(&p[curb * (RANKS * HDIM) + colOff + ct * 16 + col], cur);
                            curb = bgs[r];
                            cur = 0.f;
                        }
                        cur += acc[ct][r] + b2v;
                    }
                }
                if (curb >= 0) atomicAdd(&p[curb * (RANKS * HDIM) + colOff + ct * 16 + col], cur);
            }
        }
    }
}

// ---------------------------------------------------------------------------
__global__ void final_kernel(const float* __restrict__ p, const float* __restrict__ w1,
                             const float* __restrict__ b1, const float* __restrict__ w2,
                             const float* __restrict__ b2, float* __restrict__ out) {
    const int g = blockIdx.x;
    const int c = threadIdx.x;
    const float* pg = p + g * (RANKS * HDIM);
    float acc = b1[c];
    for (int k = 0; k < RANKS * HDIM; ++k) acc = fmaf(pg[k], w1[k * HDIM + c], acc);
    float z = siluf_(acc);
    float v = z * w2[c];
#pragma unroll
    for (int off = 32; off > 0; off >>= 1) v += __shfl_down(v, off, 64);
    __shared__ float red[2];
    if ((c & 63) == 0) red[c >> 6] = v;
    __syncthreads();
    if (c == 0) out[g] = red[0] + red[1] + b2[0];
}

// ---------------------------------------------------------------------------
extern "C" void kernel_launch(void* const* d_in, const int* in_sizes, int n_in,
                              void* d_out, int out_size, void* d_ws, size_t ws_size,
                              hipStream_t stream) {
    const float* x0 = (const float*)d_in[0];
    const float* x1 = (const float*)d_in[1];
    const int* b1_rows = (const int*)d_in[3];
    const int* b1_cols = (const int*)d_in[4];
    const int* b2_rows = (const int*)d_in[5];
    const int* b2_cols = (const int*)d_in[6];
    const int* batch0 = (const int*)d_in[7];
    const int* batch1 = (const int*)d_in[8];
    const int* batch2 = (const int*)d_in[9];
    const float* w_emb = (const float*)d_in[10];
    const float* b_emb = (const float*)d_in[11];
    const float* conv_w = (const float*)d_in[12];
    const float* pre_w1 = (const float*)d_in[13];
    const float* pre_b1 = (const float*)d_in[14];
    const float* pre_w2 = (const float*)d_in[15];
    const float* pre_b2 = (const float*)d_in[16];
    const float* post_w1 = (const float*)d_in[17];
    const float* post_b1 = (const float*)d_in[18];
    const float* post_w2 = (const float*)d_in[19];
    const float* post_b2 = (const float*)d_in[20];

    const int N0 = in_sizes[0] / NIN_;
    const int N1 = in_sizes[1] / NIN_;
    const int N2 = in_sizes[2] / NIN_;
    const int NNZ1 = in_sizes[3];
    const int NNZ2 = in_sizes[5];
    const int L = in_sizes[12] / (2 * HDIM * HDIM);
    const int Gn = out_size;

    // ws: A(bf16) | B(bf16) | C(bf16) | p(f32) | wt(bf16 weights)
    u16* A = (u16*)d_ws;
    u16* B = A + (size_t)N0 * HDIM;
    u16* C = B + (size_t)N1 * HDIM;
    float* p = (float*)(C + (size_t)N2 * HDIM);
    u16* wt = (u16*)(p + (size_t)Gn * RANKS * HDIM);
    const u16* wt_conv = wt;                            // [2L][16384]
    const u16* wt_p1 = wt + (size_t)2 * L * 16384;      // [3][16384]
    const u16* wt_p2 = wt_p1 + (size_t)3 * 16384;       // [3][16384]

    constexpr int TR = 16;
    const int ZB = 2048;

    // 0) weight pre-transform (transpose + bf16 + swizzle)
    {
        int tot = (2 * L + 6) * 16384;
        wprep_kernel<<<(tot + 255) / 256, 256, 0, stream>>>(conv_w, pre_w1, pre_w2, wt, L);
    }
    // 1) rank-0 embedding (rank-2 emb dead; rank-1 only if L==1)
    embed_bf_kernel<TR><<<(N0 + TR - 1) / TR, HDIM, 0, stream>>>(x0, w_emb, b_emb, A, N0);

    // 2) layers
    for (int l = 0; l < L; ++l) {
        const bool last = (l == L - 1);
        const u16* wr1 = wt_conv + (size_t)(l * 2 + 0) * 16384;
        const u16* wr2 = wt_conv + (size_t)(l * 2 + 1) * 16384;

        if (last) {
            if (L == 1)
                embed_bf_kernel<TR><<<(N1 + TR - 1) / TR, HDIM, 0, stream>>>(x1, w_emb, b_emb, B, N1);
            zero_kernel<<<ZB, 256, 0, stream>>>((u32*)C, (long long)N2 * (HDIM / 2));
            long long tot2 = (long long)NNZ2 * 64;
            scatter_bf_kernel<<<(int)((tot2 + 255) / 256), 256, 0, stream>>>(
                (const u32*)B, b2_rows, b2_cols, (u32*)C, NNZ2);
        }
        zero_kernel<<<ZB, 256, 0, stream>>>((u32*)B, (long long)N1 * (HDIM / 2));
        long long tot1 = (long long)NNZ1 * 64;
        scatter_bf_kernel<<<(int)((tot1 + 255) / 256), 256, 0, stream>>>(
            (const u32*)A, b1_rows, b1_cols, (u32*)B, NNZ1);

        conv_mfma_kernel<<<(N1 + 127) / 128, 512, 0, stream>>>(B, wr1, N1);
        if (last)
            conv_mfma_kernel<<<(N2 + 127) / 128, 512, 0, stream>>>(C, wr2, N2);
        if (!last)  // last-layer sigmoid(h0) is fused into prepool rank 0
            sigmoid_bf_kernel<<<2048, 256, 0, stream>>>((u32*)A, (long long)N0 * (HDIM / 2));
    }

    // 3) fused pre_pool + pooling (MFMA)
    zero_kernel<<<64, 256, 0, stream>>>((u32*)p, (long long)Gn * RANKS * HDIM);
    prepool_mfma_kernel<<<(N0 + 127) / 128, 512, 0, stream>>>(
        A, wt_p1 + 0 * 16384, wt_p2 + 0 * 16384, pre_b1 + 0 * HDIM, pre_b2 + 0 * HDIM,
        batch0, p, N0, 0 * HDIM, 1);
    prepool_mfma_kernel<<<(N1 + 127) / 128, 512, 0, stream>>>(
        B, wt_p1 + 1 * 16384, wt_p2 + 1 * 16384, pre_b1 + 1 * HDIM, pre_b2 + 1 * HDIM,
        batch1, p, N1, 1 * HDIM, 0);
    prepool_mfma_kernel<<<(N2 + 127) / 128, 512, 0, stream>>>(
        C, wt_p1 + 2 * 16384, wt_p2 + 2 * 16384, pre_b1 + 2 * HDIM, pre_b2 + 2 * HDIM,
        batch2, p, N2, 2 * HDIM, 0);

    // 4) head
    final_kernel<<<Gn, HDIM, 0, stream>>>(p, post_w1, post_b1, post_w2, post_b2, (float*)d_out);
}

// Round 6
// 2244.844 us; speedup vs baseline: 2.2309x; 1.2768x over previous
//
#include <hip/hip_runtime.h>
#include <math.h>

#define HDIM 128
#define NIN_ 32
#define RANKS 3

typedef unsigned int u32;
typedef unsigned short u16;
typedef __attribute__((ext_vector_type(8))) short short8;
typedef __attribute__((ext_vector_type(8))) __bf16 bf16x8;
typedef __attribute__((ext_vector_type(4))) float f32x4;

__device__ __forceinline__ float bf2f(u16 b) { return __uint_as_float(((u32)b) << 16); }
__device__ __forceinline__ u16 f2bf(float f) {
    u32 u = __float_as_uint(f);
    u32 r = u + 0x7fffu + ((u >> 16) & 1u);
    return (u16)(r >> 16);
}
__device__ __forceinline__ float sigmoidf_(float x) { return 1.0f / (1.0f + expf(-x)); }
__device__ __forceinline__ float siluf_(float x) { return x / (1.0f + expf(-x)); }

// ---------------------------------------------------------------------------
__global__ void zero_kernel(u32* __restrict__ p, long long nw) {
    long long i = (long long)blockIdx.x * blockDim.x + threadIdx.x;
    long long stride = (long long)gridDim.x * blockDim.x;
    for (; i < nw; i += stride) p[i] = 0u;
}

// ---------------------------------------------------------------------------
// CSR build: histogram -> hierarchical exclusive scan -> cursor fill
// ---------------------------------------------------------------------------
__global__ void count_kernel(const int* __restrict__ cols, int* __restrict__ cnt, int nnz) {
    int e = blockIdx.x * 256 + threadIdx.x;
    if (e < nnz) atomicAdd(&cnt[cols[e]], 1);
}

__global__ void scan1_kernel(const int* __restrict__ cnt, int* __restrict__ bsum, int ndst) {
    __shared__ int lds[256];
    int base = blockIdx.x * 1024, t = threadIdx.x;
    int s = 0;
#pragma unroll
    for (int j = 0; j < 4; ++j) {
        int i = base + t * 4 + j;
        s += (i < ndst) ? cnt[i] : 0;
    }
    lds[t] = s;
    __syncthreads();
    for (int off = 128; off > 0; off >>= 1) {
        if (t < off) lds[t] += lds[t + off];
        __syncthreads();
    }
    if (t == 0) bsum[blockIdx.x] = lds[0];
}

// parallel exclusive scan of up to 2048 block sums (single block)
__global__ void scan2_kernel(int* __restrict__ bsum, int nb, int* __restrict__ total) {
    __shared__ int lds[256];
    int t = threadIdx.x;
    int v[8];
    int s = 0;
#pragma unroll
    for (int j = 0; j < 8; ++j) {
        int i = t * 8 + j;
        v[j] = (i < nb) ? bsum[i] : 0;
        s += v[j];
    }
    lds[t] = s;
    __syncthreads();
    for (int off = 1; off < 256; off <<= 1) {
        int y = (t >= off) ? lds[t - off] : 0;
        __syncthreads();
        lds[t] += y;
        __syncthreads();
    }
    int run = lds[t] - s;  // exclusive base for this thread
#pragma unroll
    for (int j = 0; j < 8; ++j) {
        int i = t * 8 + j;
        if (i < nb) {
            bsum[i] = run;
            run += v[j];
        }
    }
    if (t == 255) *total = run;
}

__global__ void scan3_kernel(const int* __restrict__ cnt, const int* __restrict__ bsum,
                             int* __restrict__ rowptr, int* __restrict__ cursor, int ndst) {
    __shared__ int lds[256];
    int base = blockIdx.x * 1024, t = threadIdx.x;
    int v[4];
    int s = 0;
#pragma unroll
    for (int j = 0; j < 4; ++j) {
        int i = base + t * 4 + j;
        v[j] = (i < ndst) ? cnt[i] : 0;
        s += v[j];
    }
    lds[t] = s;
    __syncthreads();
    for (int off = 1; off < 256; off <<= 1) {
        int y = (t >= off) ? lds[t - off] : 0;
        __syncthreads();
        lds[t] += y;
        __syncthreads();
    }
    int run = bsum[blockIdx.x] + lds[t] - s;
#pragma unroll
    for (int j = 0; j < 4; ++j) {
        int i = base + t * 4 + j;
        if (i < ndst) {
            rowptr[i] = run;
            cursor[i] = run;
            run += v[j];
        }
    }
}

__global__ void fill_kernel(const int* __restrict__ rows, const int* __restrict__ cols,
                            int* __restrict__ cursor, int* __restrict__ esrc, int nnz) {
    int e = blockIdx.x * 256 + threadIdx.x;
    if (e >= nnz) return;
    int idx = atomicAdd(&cursor[cols[e]], 1);
    esrc[idx] = rows[e];
}

// ---------------------------------------------------------------------------
// h(bf16) = x(f32) @ w_emb + b_emb
// ---------------------------------------------------------------------------
template <int TR>
__global__ void embed_bf_kernel(const float* __restrict__ x, const float* __restrict__ w,
                                const float* __restrict__ b, u16* __restrict__ h, int n) {
    __shared__ float xs[TR][NIN_];
    const int row0 = blockIdx.x * TR;
    const int c = threadIdx.x;

    for (int i = c; i < TR * NIN_; i += HDIM) {
        int r = i >> 5, k = i & 31;
        int gr = row0 + r;
        xs[r][k] = (gr < n) ? x[(long long)gr * NIN_ + k] : 0.0f;
    }
    __syncthreads();

    float acc[TR];
    const float bias = b[c];
#pragma unroll
    for (int r = 0; r < TR; ++r) acc[r] = bias;
    for (int k = 0; k < NIN_; ++k) {
        float wv = w[k * HDIM + c];
#pragma unroll
        for (int r = 0; r < TR; ++r) acc[r] = fmaf(xs[r][k], wv, acc[r]);
    }
#pragma unroll
    for (int r = 0; r < TR; ++r) {
        int gr = row0 + r;
        if (gr < n) h[(long long)gr * HDIM + c] = f2bf(acc[r]);
    }
}

// ---------------------------------------------------------------------------
// Weight pre-transform: wt[m][col*128 + (k ^ ((col&7)<<3))] = bf16(W[m][k][col])
// ---------------------------------------------------------------------------
__global__ void wprep_kernel(const float* __restrict__ conv_w, const float* __restrict__ pre_w1,
                             const float* __restrict__ pre_w2, u16* __restrict__ wt, int Lnum) {
    int tid = blockIdx.x * 256 + threadIdx.x;
    int nm = 2 * Lnum + 6;
    if (tid >= nm * 128 * 128) return;
    int m = tid >> 14;
    int r = tid & 16383;
    int k = r >> 7;
    int col = r & 127;
    const float* src;
    if (m < 2 * Lnum) src = conv_w + (size_t)m * 16384;
    else if (m < 2 * Lnum + 3) src = pre_w1 + (size_t)(m - 2 * Lnum) * 16384;
    else src = pre_w2 + (size_t)(m - 2 * Lnum - 3) * 16384;
    float v = src[k * 128 + col];
    wt[(size_t)m * 16384 + col * 128 + (k ^ ((col & 7) << 3))] = f2bf(v);
}

// ---------------------------------------------------------------------------
// Fused message-pass + conv [+ prepool + pool].
// MODE 0: out = sigmoid(gather(sig^a(src)) @ Wconv)      -> outbuf
// MODE 1: h   = sigmoid(gather(sig^a(src)) @ Wconv);
//         z = silu(h@W1+b1); y = z@W2+b2; pool y by batch -> p (atomics)
// 512 thr / 8 waves / 128 dst rows per block. Weights restaged in 32KB LDS.
// ---------------------------------------------------------------------------
template <int MODE>
__global__ __launch_bounds__(512) void fused_mfma_kernel(
    const u16* __restrict__ srcbuf, const int* __restrict__ rowptr,
    const int* __restrict__ esrc, const u16* __restrict__ wconv,
    const u16* __restrict__ w1t, const u16* __restrict__ w2t,
    const float* __restrict__ b1, const float* __restrict__ b2,
    const int* __restrict__ batch, float* __restrict__ p, int colOff,
    u16* __restrict__ outbuf, int n, int applySig) {
    __shared__ u16 wls[16384];
    __shared__ u16 zs[8][16][128];
    const int tid = threadIdx.x;
    const int wave = tid >> 6, lane = tid & 63;
    const int row0 = blockIdx.x * 128;
    const int col = lane & 15, kg = lane >> 4;
    const int wrow0 = row0 + wave * 16;

    {   // stage conv weight (overlaps with gather's global loads)
        const uint4* g = (const uint4*)wconv;
        uint4* l = (uint4*)wls;
        for (int i = tid; i < 2048; i += 512) l[i] = g[i];
    }

    // ---- gather m-row fragments (fp32 accumulate over CSR edges) ----
    float ga[4][8];
#pragma unroll
    for (int k0 = 0; k0 < 4; ++k0)
#pragma unroll
        for (int j = 0; j < 8; ++j) ga[k0][j] = 0.f;
    const int arow = wrow0 + col;
    if (arow < n) {
        int beg = rowptr[arow], end = rowptr[arow + 1];
        if (applySig == 0) {
            for (int e = beg; e < end; ++e) {
                int srow = esrc[e];
                const bf16x8* sp = (const bf16x8*)(srcbuf + (size_t)srow * HDIM + kg * 8);
#pragma unroll
                for (int k0 = 0; k0 < 4; ++k0) {
                    short8 v = __builtin_bit_cast(short8, sp[k0 * 4]);
#pragma unroll
                    for (int j = 0; j < 8; ++j) ga[k0][j] += bf2f((u16)v[j]);
                }
            }
        } else {
            for (int e = beg; e < end; ++e) {
                int srow = esrc[e];
                const bf16x8* sp = (const bf16x8*)(srcbuf + (size_t)srow * HDIM + kg * 8);
#pragma unroll
                for (int k0 = 0; k0 < 4; ++k0) {
                    short8 v = __builtin_bit_cast(short8, sp[k0 * 4]);
#pragma unroll
                    for (int j = 0; j < 8; ++j) {
                        float f = bf2f((u16)v[j]);
                        for (int q = 0; q < applySig; ++q) f = sigmoidf_(f);
                        ga[k0][j] += f;
                    }
                }
            }
        }
    }
    bf16x8 afrag[4];
#pragma unroll
    for (int k0 = 0; k0 < 4; ++k0) {
        short8 s;
#pragma unroll
        for (int j = 0; j < 8; ++j) s[j] = (short)f2bf(ga[k0][j]);
        afrag[k0] = __builtin_bit_cast(bf16x8, s);
    }
    __syncthreads();  // wls ready

    // ---- GEMM1: m @ Wconv ----
    f32x4 acc[8];
#pragma unroll
    for (int ct = 0; ct < 8; ++ct) acc[ct] = (f32x4){0.f, 0.f, 0.f, 0.f};
#pragma unroll
    for (int ct = 0; ct < 8; ++ct) {
        int bcol = ct * 16 + col;
        const u16* bb = wls + bcol * 128;
        int swz = (bcol & 7) << 3;
#pragma unroll
        for (int k0 = 0; k0 < 4; ++k0) {
            bf16x8 bfrag = *(const bf16x8*)(bb + ((k0 * 32 + kg * 8) ^ swz));
            acc[ct] = __builtin_amdgcn_mfma_f32_16x16x32_bf16(afrag[k0], bfrag, acc[ct], 0, 0, 0);
        }
    }

    if (MODE == 0) {
        // epilogue: sigmoid -> bf16 -> swizzled LDS -> coalesced row stores
#pragma unroll
        for (int ct = 0; ct < 8; ++ct)
#pragma unroll
            for (int r = 0; r < 4; ++r) {
                int crow = kg * 4 + r;
                zs[wave][crow][(ct * 16 + col) ^ ((crow & 7) << 3)] = f2bf(sigmoidf_(acc[ct][r]));
            }
#pragma unroll
        for (int it = 0; it < 4; ++it) {
            int cid = it * 64 + lane;
            int r = cid >> 4, c = cid & 15;
            int grow = wrow0 + r;
            if (grow < n) {
                short8 v = *(const short8*)(&zs[wave][r][(c * 8) ^ ((r & 7) << 3)]);
                *(short8*)(outbuf + (size_t)grow * HDIM + c * 8) = v;
            }
        }
        return;
    }

    // ---- h = sigmoid(acc) -> zs (A-layout, swizzled) ----
#pragma unroll
    for (int ct = 0; ct < 8; ++ct)
#pragma unroll
        for (int r = 0; r < 4; ++r) {
            int crow = kg * 4 + r;
            zs[wave][crow][(ct * 16 + col) ^ ((crow & 7) << 3)] = f2bf(sigmoidf_(acc[ct][r]));
        }
    __syncthreads();
    {   // restage W1
        const uint4* g = (const uint4*)w1t;
        uint4* l = (uint4*)wls;
        for (int i = tid; i < 2048; i += 512) l[i] = g[i];
    }
    __syncthreads();

    // ---- GEMM2: z = silu(h @ W1 + b1) ----
    bf16x8 zfrag[4];
    {
        int zswz = (col & 7) << 3;
#pragma unroll
        for (int k0 = 0; k0 < 4; ++k0)
            zfrag[k0] = *(const bf16x8*)(&zs[wave][col][(k0 * 32 + kg * 8) ^ zswz]);
    }
#pragma unroll
    for (int ct = 0; ct < 8; ++ct) acc[ct] = (f32x4){0.f, 0.f, 0.f, 0.f};
#pragma unroll
    for (int ct = 0; ct < 8; ++ct) {
        int bcol = ct * 16 + col;
        const u16* bb = wls + bcol * 128;
        int swz = (bcol & 7) << 3;
#pragma unroll
        for (int k0 = 0; k0 < 4; ++k0) {
            bf16x8 bfrag = *(const bf16x8*)(bb + ((k0 * 32 + kg * 8) ^ swz));
            acc[ct] = __builtin_amdgcn_mfma_f32_16x16x32_bf16(zfrag[k0], bfrag, acc[ct], 0, 0, 0);
        }
    }
#pragma unroll
    for (int ct = 0; ct < 8; ++ct) {
        float b1v = b1[ct * 16 + col];
#pragma unroll
        for (int r = 0; r < 4; ++r) {
            int crow = kg * 4 + r;
            zs[wave][crow][(ct * 16 + col) ^ ((crow & 7) << 3)] = f2bf(siluf_(acc[ct][r] + b1v));
        }
    }
    __syncthreads();
    {   // restage W2
        const uint4* g = (const uint4*)w2t;
        uint4* l = (uint4*)wls;
        for (int i = tid; i < 2048; i += 512) l[i] = g[i];
    }
    __syncthreads();

    // ---- GEMM3: y = z @ W2 (+b2 at pooling) ----
    {
        int zswz = (col & 7) << 3;
#pragma unroll
        for (int k0 = 0; k0 < 4; ++k0)
            zfrag[k0] = *(const bf16x8*)(&zs[wave][col][(k0 * 32 + kg * 8) ^ zswz]);
    }
#pragma unroll
    for (int ct = 0; ct < 8; ++ct) acc[ct] = (f32x4){0.f, 0.f, 0.f, 0.f};
#pragma unroll
    for (int ct = 0; ct < 8; ++ct) {
        int bcol = ct * 16 + col;
        const u16* bb = wls + bcol * 128;
        int swz = (bcol & 7) << 3;
#pragma unroll
        for (int k0 = 0; k0 < 4; ++k0) {
            bf16x8 bfrag = *(const bf16x8*)(bb + ((k0 * 32 + kg * 8) ^ swz));
            acc[ct] = __builtin_amdgcn_mfma_f32_16x16x32_bf16(zfrag[k0], bfrag, acc[ct], 0, 0, 0);
        }
    }

    // ---- pooling (batch sorted) ----
    if (wrow0 < n) {
        int rend = wrow0 + 15 < n ? wrow0 + 15 : (n - 1);
        int bstart = batch[wrow0];
        int bend = batch[rend];
        if (bstart == bend) {
#pragma unroll
            for (int ct = 0; ct < 8; ++ct) {
                float b2v = b2[ct * 16 + col];
                float s = 0.f;
#pragma unroll
                for (int r = 0; r < 4; ++r) {
                    int row = wrow0 + kg * 4 + r;
                    if (row < n) s += acc[ct][r] + b2v;
                }
                s += __shfl_xor(s, 16, 64);
                s += __shfl_xor(s, 32, 64);
                if (kg == 0) atomicAdd(&p[bstart * (RANKS * HDIM) + colOff + ct * 16 + col], s);
            }
        } else {
            int bgs[4];
#pragma unroll
            for (int r = 0; r < 4; ++r) {
                int row = wrow0 + kg * 4 + r;
                bgs[r] = (row < n) ? batch[row] : -1;
            }
#pragma unroll
            for (int ct = 0; ct < 8; ++ct) {
                float b2v = b2[ct * 16 + col];
                int curb = -1;
                float cur = 0.f;
#pragma unroll
                for (int r = 0; r < 4; ++r) {
                    if (bgs[r] >= 0) {
                        if (bgs[r] != curb) {
                            if (curb >= 0)
                                atomicAdd(&p[curb * (RANKS * HDIM) + colOff + ct * 16 + col], cur);
                            curb = bgs[r];
                            cur = 0.f;
                        }
                        cur += acc[ct][r] + b2v;
                    }
                }
                if (curb >= 0) atomicAdd(&p[curb * (RANKS * HDIM) + colOff + ct * 16 + col], cur);
            }
        }
    }
}

// ---------------------------------------------------------------------------
// Rank-0 prepool (no gather/conv): y = silu(sig^presig(h)@W1+b1)@W2+b2, pooled.
// ---------------------------------------------------------------------------
__global__ __launch_bounds__(512) void prepool_mfma_kernel(
    const u16* __restrict__ h, const u16* __restrict__ w1t, const u16* __restrict__ w2t,
    const float* __restrict__ b1, const float* __restrict__ b2, const int* __restrict__ batch,
    float* __restrict__ p, int n, int colOff, int presig) {
    __shared__ u16 wls[16384];
    __shared__ u16 zs[8][16][128];
    const int tid = threadIdx.x;
    const int wave = tid >> 6, lane = tid & 63;
    const int row0 = blockIdx.x * 128;
    const int col = lane & 15, kg = lane >> 4;
    const int wrow0 = row0 + wave * 16;

    {
        const uint4* g = (const uint4*)w1t;
        uint4* l = (uint4*)wls;
        for (int i = tid; i < 2048; i += 512) l[i] = g[i];
    }
    __syncthreads();

    const int arow = wrow0 + col;
    const int arowc = arow < n ? arow : (n - 1);
    bf16x8 afrag[4];
    {
        const bf16x8* ap = (const bf16x8*)(h + (size_t)arowc * HDIM + kg * 8);
#pragma unroll
        for (int k0 = 0; k0 < 4; ++k0) afrag[k0] = ap[k0 * 4];
    }
    if (presig > 0) {
#pragma unroll
        for (int k0 = 0; k0 < 4; ++k0) {
            short8 s = __builtin_bit_cast(short8, afrag[k0]);
#pragma unroll
            for (int j = 0; j < 8; ++j) {
                float f = bf2f((u16)s[j]);
                for (int q = 0; q < presig; ++q) f = sigmoidf_(f);
                s[j] = (short)f2bf(f);
            }
            afrag[k0] = __builtin_bit_cast(bf16x8, s);
        }
    }

    f32x4 acc[8];
#pragma unroll
    for (int ct = 0; ct < 8; ++ct) acc[ct] = (f32x4){0.f, 0.f, 0.f, 0.f};
#pragma unroll
    for (int ct = 0; ct < 8; ++ct) {
        int bcol = ct * 16 + col;
        const u16* bb = wls + bcol * 128;
        int swz = (bcol & 7) << 3;
#pragma unroll
        for (int k0 = 0; k0 < 4; ++k0) {
            bf16x8 bfrag = *(const bf16x8*)(bb + ((k0 * 32 + kg * 8) ^ swz));
            acc[ct] = __builtin_amdgcn_mfma_f32_16x16x32_bf16(afrag[k0], bfrag, acc[ct], 0, 0, 0);
        }
    }
#pragma unroll
    for (int ct = 0; ct < 8; ++ct) {
        float b1v = b1[ct * 16 + col];
#pragma unroll
        for (int r = 0; r < 4; ++r) {
            int crow = kg * 4 + r;
            zs[wave][crow][(ct * 16 + col) ^ ((crow & 7) << 3)] = f2bf(siluf_(acc[ct][r] + b1v));
        }
    }
    __syncthreads();
    {
        const uint4* g = (const uint4*)w2t;
        uint4* l = (uint4*)wls;
        for (int i = tid; i < 2048; i += 512) l[i] = g[i];
    }
    __syncthreads();

    bf16x8 zfrag[4];
    {
        int zswz = (col & 7) << 3;
#pragma unroll
        for (int k0 = 0; k0 < 4; ++k0)
            zfrag[k0] = *(const bf16x8*)(&zs[wave][col][(k0 * 32 + kg * 8) ^ zswz]);
    }
#pragma unroll
    for (int ct = 0; ct < 8; ++ct) acc[ct] = (f32x4){0.f, 0.f, 0.f, 0.f};
#pragma unroll
    for (int ct = 0; ct < 8; ++ct) {
        int bcol = ct * 16 + col;
        const u16* bb = wls + bcol * 128;
        int swz = (bcol & 7) << 3;
#pragma unroll
        for (int k0 = 0; k0 < 4; ++k0) {
            bf16x8 bfrag = *(const bf16x8*)(bb + ((k0 * 32 + kg * 8) ^ swz));
            acc[ct] = __builtin_amdgcn_mfma_f32_16x16x32_bf16(zfrag[k0], bfrag, acc[ct], 0, 0, 0);
        }
    }

    if (wrow0 < n) {
        int rend = wrow0 + 15 < n ? wrow0 + 15 : (n - 1);
        int bstart = batch[wrow0];
        int bend = batch[rend];
        if (bstart == bend) {
#pragma unroll
            for (int ct = 0; ct < 8; ++ct) {
                float b2v = b2[ct * 16 + col];
                float s = 0.f;
#pragma unroll
                for (int r = 0; r < 4; ++r) {
                    int row = wrow0 + kg * 4 + r;
                    if (row < n) s += acc[ct][r] + b2v;
                }
                s += __shfl_xor(s, 16, 64);
                s += __shfl_xor(s, 32, 64);
                if (kg == 0) atomicAdd(&p[bstart * (RANKS * HDIM) + colOff + ct * 16 + col], s);
            }
        } else {
            int bgs[4];
#pragma unroll
            for (int r = 0; r < 4; ++r) {
                int row = wrow0 + kg * 4 + r;
                bgs[r] = (row < n) ? batch[row] : -1;
            }
#pragma unroll
            for (int ct = 0; ct < 8; ++ct) {
                float b2v = b2[ct * 16 + col];
                int curb = -1;
                float cur = 0.f;
#pragma unroll
                for (int r = 0; r < 4; ++r) {
                    if (bgs[r] >= 0) {
                        if (bgs[r] != curb) {
                            if (curb >= 0)
                                atomicAdd(&p[curb * (RANKS * HDIM) + colOff + ct * 16 + col], cur);
                            curb = bgs[r];
                            cur = 0.f;
                        }
                        cur += acc[ct][r] + b2v;
                    }
                }
                if (curb >= 0) atomicAdd(&p[curb * (RANKS * HDIM) + colOff + ct * 16 + col], cur);
            }
        }
    }
}

// ---------------------------------------------------------------------------
__global__ void final_kernel(const float* __restrict__ p, const float* __restrict__ w1,
                             const float* __restrict__ b1, const float* __restrict__ w2,
                             const float* __restrict__ b2, float* __restrict__ out) {
    const int g = blockIdx.x;
    const int c = threadIdx.x;
    const float* pg = p + g * (RANKS * HDIM);
    float acc = b1[c];
    for (int k = 0; k < RANKS * HDIM; ++k) acc = fmaf(pg[k], w1[k * HDIM + c], acc);
    float z = siluf_(acc);
    float v = z * w2[c];
#pragma unroll
    for (int off = 32; off > 0; off >>= 1) v += __shfl_down(v, off, 64);
    __shared__ float red[2];
    if ((c & 63) == 0) red[c >> 6] = v;
    __syncthreads();
    if (c == 0) out[g] = red[0] + red[1] + b2[0];
}

// ---------------------------------------------------------------------------
extern "C" void kernel_launch(void* const* d_in, const int* in_sizes, int n_in,
                              void* d_out, int out_size, void* d_ws, size_t ws_size,
                              hipStream_t stream) {
    const float* x0 = (const float*)d_in[0];
    const float* x1 = (const float*)d_in[1];
    const int* b1_rows = (const int*)d_in[3];
    const int* b1_cols = (const int*)d_in[4];
    const int* b2_rows = (const int*)d_in[5];
    const int* b2_cols = (const int*)d_in[6];
    const int* batch0 = (const int*)d_in[7];
    const int* batch1 = (const int*)d_in[8];
    const int* batch2 = (const int*)d_in[9];
    const float* w_emb = (const float*)d_in[10];
    const float* b_emb = (const float*)d_in[11];
    const float* conv_w = (const float*)d_in[12];
    const float* pre_w1 = (const float*)d_in[13];
    const float* pre_b1 = (const float*)d_in[14];
    const float* pre_w2 = (const float*)d_in[15];
    const float* pre_b2 = (const float*)d_in[16];
    const float* post_w1 = (const float*)d_in[17];
    const float* post_b1 = (const float*)d_in[18];
    const float* post_w2 = (const float*)d_in[19];
    const float* post_b2 = (const float*)d_in[20];

    const int N0 = in_sizes[0] / NIN_;
    const int N1 = in_sizes[1] / NIN_;
    const int N2 = in_sizes[2] / NIN_;
    const int NNZ1 = in_sizes[3];
    const int NNZ2 = in_sizes[5];
    const int L = in_sizes[12] / (2 * HDIM * HDIM);
    const int Gn = out_size;

    // ws: A (h0 raw embed) | B (h1 of layer L-1) | p | wt | CSR   (~224 MB)
    u16* A = (u16*)d_ws;
    u16* B = A + (size_t)N0 * HDIM;
    float* p = (float*)(B + (size_t)N1 * HDIM);
    u16* wt = (u16*)(p + (size_t)Gn * RANKS * HDIM);
    const u16* wt_conv = wt;                        // [2L][16384]
    const u16* wt_p1 = wt + (size_t)2 * L * 16384;  // [3][16384]
    const u16* wt_p2 = wt_p1 + (size_t)3 * 16384;   // [3][16384]
    int* ip = (int*)(wt + (size_t)(2 * L + 6) * 16384);
    int* rowptr1 = ip;  ip += N1 + 1;
    int* rowptr2 = ip;  ip += N2 + 1;
    int* esrc1 = ip;    ip += NNZ1;
    int* esrc2 = ip;    ip += NNZ2;
    int maxN = N1 > N2 ? N1 : N2;
    int* cnt = ip;      ip += maxN;
    int* cursor = ip;   ip += maxN;
    int* bsum = ip;     ip += 2048;

    constexpr int TR = 16;

    // 0) weight pre-transform + CSR builds
    {
        int tot = (2 * L + 6) * 16384;
        wprep_kernel<<<(tot + 255) / 256, 256, 0, stream>>>(conv_w, pre_w1, pre_w2, wt, L);

        zero_kernel<<<512, 256, 0, stream>>>((u32*)cnt, N1);
        count_kernel<<<(NNZ1 + 255) / 256, 256, 0, stream>>>(b1_cols, cnt, NNZ1);
        int nb1 = (N1 + 1023) / 1024;
        scan1_kernel<<<nb1, 256, 0, stream>>>(cnt, bsum, N1);
        scan2_kernel<<<1, 256, 0, stream>>>(bsum, nb1, rowptr1 + N1);
        scan3_kernel<<<nb1, 256, 0, stream>>>(cnt, bsum, rowptr1, cursor, N1);
        fill_kernel<<<(NNZ1 + 255) / 256, 256, 0, stream>>>(b1_rows, b1_cols, cursor, esrc1, NNZ1);

        zero_kernel<<<512, 256, 0, stream>>>((u32*)cnt, N2);
        count_kernel<<<(NNZ2 + 255) / 256, 256, 0, stream>>>(b2_cols, cnt, NNZ2);
        int nb2 = (N2 + 1023) / 1024;
        scan1_kernel<<<nb2, 256, 0, stream>>>(cnt, bsum, N2);
        scan2_kernel<<<1, 256, 0, stream>>>(bsum, nb2, rowptr2 + N2);
        scan3_kernel<<<nb2, 256, 0, stream>>>(cnt, bsum, rowptr2, cursor, N2);
        fill_kernel<<<(NNZ2 + 255) / 256, 256, 0, stream>>>(b2_rows, b2_cols, cursor, esrc2, NNZ2);
    }

    // 1) rank-0 embedding into A (raw; sigmoids applied lazily downstream)
    embed_bf_kernel<TR><<<(N0 + TR - 1) / TR, HDIM, 0, stream>>>(x0, w_emb, b_emb, A, N0);

    // 2) B = h1 entering the last layer.
    //    L>=2: B = sigmoid(gather(sig^(L-2)(A)) @ conv_w[L-2,0])  (earlier h1 dead)
    //    L==1: B = embed(x1)
    if (L >= 2) {
        fused_mfma_kernel<0><<<(N1 + 127) / 128, 512, 0, stream>>>(
            A, rowptr1, esrc1, wt_conv + (size_t)((L - 2) * 2 + 0) * 16384,
            nullptr, nullptr, nullptr, nullptr, nullptr, nullptr, 0, B, N1, L - 2);
    } else {
        embed_bf_kernel<TR><<<(N1 + TR - 1) / TR, HDIM, 0, stream>>>(x1, w_emb, b_emb, B, N1);
    }

    // 3) pooled state
    zero_kernel<<<64, 256, 0, stream>>>((u32*)p, (long long)Gn * RANKS * HDIM);

    // rank 2: gather(B) -> conv[L-1,1] -> prepool[2] -> pool
    fused_mfma_kernel<1><<<(N2 + 127) / 128, 512, 0, stream>>>(
        B, rowptr2, esrc2, wt_conv + (size_t)((L - 1) * 2 + 1) * 16384,
        wt_p1 + 2 * 16384, wt_p2 + 2 * 16384, pre_b1 + 2 * HDIM, pre_b2 + 2 * HDIM,
        batch2, p, 2 * HDIM, nullptr, N2, 0);

    // rank 1: gather(sig^(L-1)(A)) -> conv[L-1,0] -> prepool[1] -> pool
    fused_mfma_kernel<1><<<(N1 + 127) / 128, 512, 0, stream>>>(
        A, rowptr1, esrc1, wt_conv + (size_t)((L - 1) * 2 + 0) * 16384,
        wt_p1 + 1 * 16384, wt_p2 + 1 * 16384, pre_b1 + 1 * HDIM, pre_b2 + 1 * HDIM,
        batch1, p, 1 * HDIM, nullptr, N1, L - 1);

    // rank 0: sig^L(A) -> prepool[0] -> pool
    prepool_mfma_kernel<<<(N0 + 127) / 128, 512, 0, stream>>>(
        A, wt_p1 + 0 * 16384, wt_p2 + 0 * 16384, pre_b1 + 0 * HDIM, pre_b2 + 0 * HDIM,
        batch0, p, N0, 0 * HDIM, L);

    // 4) head
    final_kernel<<<Gn, HDIM, 0, stream>>>(p, post_w1, post_b1, post_w2, post_b2, (float*)d_out);
}